// Round 1
// baseline (661.447 us; speedup 1.0000x reference)
//
#include <hip/hip_runtime.h>

// Problem constants (fixed-shape problem)
#define B_ 16
#define T_ 192
#define U_ 64
#define H_ 512

// ---------------------------------------------------------------------------
// Kernel 1: per-(b,t,u) row logsumexp over H=512, emit
//   lp_blank[b,t,u] = x[b,t,u,blank] - denom
//   lp_label[b,t,u] = x[b,t,u,label[b,u]] - denom   (u < U-1, else 0)
// One wave (64 lanes) per row; 4 waves per 256-thread block.
// Memory-bound: reads 402 MB of x in one coalesced pass.
// ---------------------------------------------------------------------------
__global__ __launch_bounds__(256) void tl_lse_kernel(
    const float* __restrict__ x,
    const int* __restrict__ label,
    const int* __restrict__ blank_idx,
    float* __restrict__ lp_blank,
    float* __restrict__ lp_label) {
  const int wave = threadIdx.x >> 6;
  const int lane = threadIdx.x & 63;
  const long long row = (long long)blockIdx.x * 4 + wave;  // 0 .. B*T*U-1

  const float* __restrict__ xr = x + (row << 9);  // row * 512
  const float4* __restrict__ xv = (const float4*)xr;

  // Two coalesced float4 loads: lane i covers [4i,4i+4) and [256+4i, 256+4i+4)
  float4 p0 = xv[lane];
  float4 p1 = xv[lane + 64];

  float m = fmaxf(fmaxf(fmaxf(p0.x, p0.y), fmaxf(p0.z, p0.w)),
                  fmaxf(fmaxf(p1.x, p1.y), fmaxf(p1.z, p1.w)));
#pragma unroll
  for (int d = 32; d > 0; d >>= 1) m = fmaxf(m, __shfl_xor(m, d, 64));

  float s = __expf(p0.x - m) + __expf(p0.y - m) + __expf(p0.z - m) +
            __expf(p0.w - m) + __expf(p1.x - m) + __expf(p1.y - m) +
            __expf(p1.z - m) + __expf(p1.w - m);
#pragma unroll
  for (int d = 32; d > 0; d >>= 1) s += __shfl_xor(s, d, 64);

  const float denom = m + __logf(s);

  if (lane == 0) {
    const int u = (int)(row & (U_ - 1));
    const int bt = (int)(row >> 6);  // b*T + t
    const int b = bt / T_;
    const int blk = blank_idx[0];
    lp_blank[row] = xr[blk] - denom;  // L1 hit: row just read
    float ll = 0.0f;
    if (u < U_ - 1) {
      const int lab = label[b * (U_ - 1) + u];
      ll = xr[lab] - denom;  // L1 hit
    }
    lp_label[row] = ll;  // pad u==U-1 with 0 (unused by exclusive scan)
  }
}

// ---------------------------------------------------------------------------
// Kernel 2: per-batch alpha recursion. One wave per batch (16 blocks x 64).
//   alpha_0 = cs[:,0,:]
//   alpha_t = cs_t + cumlogsumexp(alpha_{t-1} + lpb_{t-1} - cs_t, axis=u)
// cs computed on the fly via exclusive shuffle prefix-sum of lp_label row.
// cumlogsumexp via 6-step shuffle scan in (max, sum) representation.
// ---------------------------------------------------------------------------
__global__ __launch_bounds__(64) void tl_alpha_kernel(
    const float* __restrict__ lp_blank,
    const float* __restrict__ lp_label,
    const int* __restrict__ f_len,
    const int* __restrict__ y_len,
    float* __restrict__ out) {
  const int b = blockIdx.x;
  const int lane = threadIdx.x;
  const int tl = f_len[b] - 1;   // >= 95 for this problem
  const int ul = y_len[b];       // <= 63

  const float* __restrict__ lpb = lp_blank + (long long)b * T_ * U_;
  const float* __restrict__ lpl = lp_label + (long long)b * T_ * U_;

  // exclusive prefix sum across the wave
  auto excl_scan = [&](float v) -> float {
    float xv = v;
#pragma unroll
    for (int d = 1; d < 64; d <<= 1) {
      float o = __shfl_up(xv, d, 64);
      if (lane >= d) xv += o;
    }
    float e = __shfl_up(xv, 1, 64);
    return (lane == 0) ? 0.0f : e;
  };

  // alpha0 = cs at t=0
  float alpha = excl_scan(lpl[lane]);

  for (int t = 1; t <= tl; ++t) {
    const float lpl_t = lpl[t * U_ + lane];
    const float lpb_tm1 = lpb[(t - 1) * U_ + lane];
    const float cs_t = excl_scan(lpl_t);
    const float v = alpha + lpb_tm1 - cs_t;

    // inclusive prefix logsumexp of v across lanes (stable (m,s) form)
    float m = v, s = 1.0f;
#pragma unroll
    for (int d = 1; d < 64; d <<= 1) {
      float m2 = __shfl_up(m, d, 64);
      float s2 = __shfl_up(s, d, 64);
      if (lane >= d) {
        const float nm = fmaxf(m, m2);
        s = s * __expf(m - nm) + s2 * __expf(m2 - nm);
        m = nm;
      }
    }
    alpha = cs_t + m + __logf(s);
  }

  if (lane == ul) {
    out[b] = -(alpha + lpb[tl * U_ + lane]);
  }
}

extern "C" void kernel_launch(void* const* d_in, const int* in_sizes, int n_in,
                              void* d_out, int out_size, void* d_ws,
                              size_t ws_size, hipStream_t stream) {
  const float* x = (const float*)d_in[0];
  const int* label = (const int*)d_in[1];
  const int* f_len = (const int*)d_in[2];
  const int* y_len = (const int*)d_in[3];
  const int* blank_idx = (const int*)d_in[4];
  float* out = (float*)d_out;

  float* lp_blank = (float*)d_ws;                       // B*T*U floats
  float* lp_label = lp_blank + (size_t)B_ * T_ * U_;    // B*T*U floats

  const int rows = B_ * T_ * U_;          // 196608
  const int blocks = rows / 4;            // 4 waves (rows) per block

  tl_lse_kernel<<<blocks, 256, 0, stream>>>(x, label, blank_idx, lp_blank,
                                            lp_label);
  tl_alpha_kernel<<<B_, 64, 0, stream>>>(lp_blank, lp_label, f_len, y_len,
                                         out);
}